// Round 15
// baseline (56.498 us; speedup 1.0000x reference)
//
#include <hip/hip_runtime.h>

#define SEQ 512
#define NBAT 512
#define NT 96
#define G 32
#define P 64
#define SEGL (SEQ / P)     // 8 steps per segment
#define OV 3               // warm-up overlap (contraction ~10x/step -> 1e-3)
#define STRIDE 104
#define LN2 0.69314718055994531f

typedef float f32x16 __attribute__((ext_vector_type(16)));
typedef short bf16x8 __attribute__((ext_vector_type(8)));

static __device__ __forceinline__ short f2bf(float f) {
    unsigned u = __float_as_uint(f);
    u += 0x7FFFu + ((u >> 16) & 1u);       // RNE (setup only)
    return (short)(u >> 16);
}
static __device__ __forceinline__ float bf2f(short s) {
    return __uint_as_float(((unsigned)(unsigned short)s) << 16);
}
static __device__ __forceinline__ unsigned pk2(float lo, float hi) {
    unsigned r;
    asm("v_cvt_pk_bf16_f32 %0, %1, %2" : "=v"(r) : "v"(lo), "v"(hi));
    return r;
}
static __device__ __forceinline__ float sum48(const uint2* pv) {
    float s = 0.f;
#pragma unroll
    for (int q = 0; q < 12; ++q) {
        s += bf2f((short)(pv[q].x & 0xFFFF)) + bf2f((short)(pv[q].x >> 16))
           + bf2f((short)(pv[q].y & 0xFFFF)) + bf2f((short)(pv[q].y >> 16));
    }
    return s;
}

// ONE WAVE per (segment, 32-batch group). The wave computes the full 96x32
// step update itself (3 j-tiles x 6 K-chunks of 32x32x16 MFMA), so the state
// exchange is same-wave LDS write->read: in-order, ZERO barriers. Emissions
// stream via global_load_lds (12 x 16B, double-buffered [24][32][4] tile,
// counted vmcnt(12) -- never drained). Scale ledger fully in registers
// (h0->h1 broadcast via one shfl_xor(32)). Segmented telescoping as R11-R14.
__launch_bounds__(64, 1)
__global__ void crf_1w(const float* __restrict__ logits,
                       const int*   __restrict__ tags,
                       const int*   __restrict__ mask,
                       const float* __restrict__ trans,
                       const float* __restrict__ startt,
                       const float* __restrict__ endt,
                       float* __restrict__ out)
{
    const int sid = blockIdx.x & (P - 1);
    const int grp = blockIdx.x >> 6;
    const int b0 = grp * G;
    const int l = threadIdx.x;     // 0..63
    const int n = l & 31;          // batch column
    const int h = l >> 5;          // half 0/1

    const int i0 = sid ? sid * SEGL - OV : 0;
    const int qs = sid * SEGL;
    const int i1 = (sid == P - 1) ? SEQ - 1 : (sid + 1) * SEGL;

    __shared__ short AT[G][STRIDE];                 // bf16 state (single buffer)
    __shared__ __align__(16) float EM[2][24][G][4]; // em tile [buf][jc][n][4]

    // E^T A-fragments: ea[T][c][e] = bf16(exp(trans[(16c+8h+e)][32T+n]))
    bf16x8 ea[3][6];
#pragma unroll
    for (int T = 0; T < 3; ++T)
#pragma unroll
        for (int c = 0; c < 6; ++c)
#pragma unroll
            for (int e = 0; e < 8; ++e)
                ea[T][c][e] = f2bf(__expf(trans[(16 * c + 8 * h + e) * NT + 32 * T + n]));

    const float* emg = logits + (size_t)(b0 + n) * SEQ * NT;

    // mask window bits (<= 12 steps)
    unsigned mybits = 0;
    {
        const int* mrow = mask + (size_t)(b0 + n) * SEQ + i0;
        const int wlen = i1 - i0 + 1;
        for (int d = 0; d < wlen; ++d) if (mrow[d]) mybits |= 1u << d;
    }

    // init state at i0 (regs + LDS), scale ledger
    uint2 prev[3][4];
    int K = 0, kcur = 0;
    float sc;
    {
        float a00ref = 1.f;
#pragma unroll
        for (int T = 0; T < 3; ++T)
#pragma unroll
            for (int p = 0; p < 4; ++p) {
                uint2 pv;
                if (sid == 0) {
                    const int j = 32 * T + 8 * p + 4 * h;
                    const float v0 = __expf(startt[j + 0] + emg[j + 0]);
                    const float v1 = __expf(startt[j + 1] + emg[j + 1]);
                    const float v2 = __expf(startt[j + 2] + emg[j + 2]);
                    const float v3 = __expf(startt[j + 3] + emg[j + 3]);
                    if (T == 0 && p == 0) a00ref = v0;   // valid on h==0
                    pv.x = pk2(v0, v1); pv.y = pk2(v2, v3);
                } else {
                    pv.x = 0x3F803F80u; pv.y = 0x3F803F80u;   // ones
                }
                prev[T][p] = pv;
                *(uint2*)&AT[n][32 * T + 8 * p + 4 * h] = pv;
            }
        if (sid == 0) kcur = (int)((__float_as_uint(a00ref) >> 23) & 0xFFu) - 127;
        const float scn = __uint_as_float((unsigned)(127 - kcur) << 23);
        const float tmp = __shfl_xor(scn, 32);
        sc = h ? tmp : scn;
    }

    // em source: lane covers j-chunks (2k+h) of its batch; dest is linear
    const char* embase = (const char*)logits
                       + (size_t)(b0 + n) * SEQ * NT * 4 + h * 16;

    // prologue: tile for step i0+1 -> buf 1
    {
        const char* gp = embase + (size_t)(i0 + 1) * 384;
#pragma unroll
        for (int k = 0; k < 12; ++k)
            __builtin_amdgcn_global_load_lds((const float*)(gp + k * 32),
                                             &EM[1][2 * k][0][0], 16, 0, 0);
    }

    float Lin = 0.f;

    for (int i = i0 + 1; i <= i1; ++i) {
        const int d = i - i0;
        const int cur = d & 1, nb = cur ^ 1;

        // issue next tile (stays in flight; counted wait below)
        {
            const int ipn = (i + 1 <= i1) ? i + 1 : i1;
            const char* gp = embase + (size_t)ipn * 384;
#pragma unroll
            for (int k = 0; k < 12; ++k)
                __builtin_amdgcn_global_load_lds((const float*)(gp + k * 32),
                                                 &EM[nb][2 * k][0][0], 16, 0, 0);
        }
        asm volatile("s_waitcnt vmcnt(12)" ::: "memory");   // step-i tile landed

        // read previous state (in-order vs the writes below: same wave)
        bf16x8 Bf[6];
#pragma unroll
        for (int c = 0; c < 6; ++c)
            Bf[c] = *(const bf16x8*)&AT[n][16 * c + 8 * h];

        f32x16 acc[3];
#pragma unroll
        for (int T = 0; T < 3; ++T)
#pragma unroll
            for (int e = 0; e < 16; ++e) acc[T][e] = 0.f;
#pragma unroll
        for (int c = 0; c < 6; ++c) {
            acc[0] = __builtin_amdgcn_mfma_f32_32x32x16_bf16(ea[0][c], Bf[c], acc[0], 0, 0, 0);
            acc[1] = __builtin_amdgcn_mfma_f32_32x32x16_bf16(ea[1][c], Bf[c], acc[1], 0, 0, 0);
            acc[2] = __builtin_amdgcn_mfma_f32_32x32x16_bf16(ea[2][c], Bf[c], acc[2], 0, 0, 0);
        }

        const unsigned mk = (mybits >> d) & 1u;
        float a00 = 1.f;
#pragma unroll
        for (int T = 0; T < 3; ++T)
#pragma unroll
            for (int p = 0; p < 4; ++p) {
                const float4 emv = *(const float4*)&EM[cur][8 * T + 2 * p + h][n][0];
                const float av0 = acc[T][4 * p + 0] * (__expf(emv.x) * sc);
                const float av1 = acc[T][4 * p + 1] * (__expf(emv.y) * sc);
                const float av2 = acc[T][4 * p + 2] * (__expf(emv.z) * sc);
                const float av3 = acc[T][4 * p + 3] * (__expf(emv.w) * sc);
                if (T == 0 && p == 0) a00 = av0;          // row 0 on h==0 lanes
                uint2 nw; nw.x = pk2(av0, av1); nw.y = pk2(av2, av3);
                if (mk) prev[T][p] = nw;
                *(uint2*)&AT[n][32 * T + 8 * p + 4 * h] = prev[T][p];
            }

        if (mk) { K += kcur; kcur = (int)((__float_as_uint(a00) >> 23) & 0xFFu) - 127; }
        {
            const float scn = __uint_as_float((unsigned)(127 - kcur) << 23);
            const float tmp = __shfl_xor(scn, 32);
            const float scb = h ? tmp : scn;
            sc = mk ? scb : sc;
        }

        if (sid && d == OV) {   // Lin snapshot (state after step qs)
            float s1 = sum48(&prev[0][0]);
            s1 += __shfl_xor(s1, 32);
            Lin = __logf(s1) + (float)K * LN2;   // valid on h==0
        }
    }

    // Lout (mid segments) or Lend (last): in-register
    float LoutEnd;
    {
        float s = 0.f;
        if (sid == P - 1) {
#pragma unroll
            for (int T = 0; T < 3; ++T)
#pragma unroll
                for (int p = 0; p < 4; ++p) {
                    const int j = 32 * T + 8 * p + 4 * h;
                    s += bf2f((short)(prev[T][p].x & 0xFFFF)) * __expf(endt[j + 0])
                       + bf2f((short)(prev[T][p].x >> 16))    * __expf(endt[j + 1])
                       + bf2f((short)(prev[T][p].y & 0xFFFF)) * __expf(endt[j + 2])
                       + bf2f((short)(prev[T][p].y >> 16))    * __expf(endt[j + 3]);
                }
        } else {
            s = sum48(&prev[0][0]);
        }
        s += __shfl_xor(s, 32);
        LoutEnd = __logf(s) + (float)K * LN2;
    }

    // numerator partials over steps qs+1..i1 (split across h)
    float pn = 0.f;
    {
        const int* tgp = tags + (size_t)(b0 + n) * SEQ;
        for (int i = qs + 1 + h; i <= i1; i += 2) {
            if (mask[(size_t)(b0 + n) * SEQ + i]) {
                const int tp = tgp[i - 1], tc = tgp[i];
                pn += trans[tp * NT + tc] + emg[(size_t)i * NT + tc];
            }
        }
    }
    int cnt = 0;
    if (sid == P - 1) {
        const int4* m4p = (const int4*)(mask + (size_t)(b0 + n) * SEQ);
        for (int k = h; k < SEQ / 4; k += 2) {
            const int4 m4 = m4p[k];
            cnt += (m4.x != 0) + (m4.y != 0) + (m4.z != 0) + (m4.w != 0);
        }
    }
    pn  += __shfl_xor(pn, 32);
    cnt += __shfl_xor(cnt, 32);

    float v = 0.f;
    if (h == 0) {
        float num = pn;
        const int* tgq = tags + (size_t)(b0 + n) * SEQ;
        if (sid == 0)     num += startt[tgq[0]] + emg[tgq[0]];
        if (sid == P - 1) num += endt[tgq[cnt - 1]];
        v = num - LoutEnd + Lin;           // telescoping contribution
    }
    v += __shfl_xor(v, 1);
    v += __shfl_xor(v, 2);
    v += __shfl_xor(v, 4);
    v += __shfl_xor(v, 8);
    v += __shfl_xor(v, 16);
    v += __shfl_xor(v, 32);
    if (l == 0) atomicAdd(out, v);
}

extern "C" void kernel_launch(void* const* d_in, const int* in_sizes, int n_in,
                              void* d_out, int out_size, void* d_ws, size_t ws_size,
                              hipStream_t stream)
{
    const float* logits = (const float*)d_in[0];
    const int*   tags   = (const int*)  d_in[1];
    const int*   mask   = (const int*)  d_in[2];
    const float* trans  = (const float*)d_in[3];
    const float* startt = (const float*)d_in[4];
    const float* endt   = (const float*)d_in[5];
    float* out = (float*)d_out;

    hipMemsetAsync(out, 0, out_size * sizeof(float), stream);
    crf_1w<<<(NBAT / G) * P, 64, 0, stream>>>(logits, tags, mask, trans,
                                              startt, endt, out);
}

// Round 17
// 50.908 us; speedup vs baseline: 1.1098x; 1.1098x over previous
//
#include <hip/hip_runtime.h>

#define SEQ 512
#define NBAT 512
#define NT 96
#define G 32
#define P 64
#define SEGL (SEQ / P)        // 8 steps per segment
#define OV 3                  // warm-up overlap (contraction ~10x/step -> 1e-3)
#define TPB 192               // 3 waves; wave T owns j-tile [32T, 32T+32)
#define STRIDE 104            // shorts; 208B row = 13 x 16B
#define FSH 7                 // fixed per-step rescale 2^-7 (folded into ea)
#define LN2 0.69314718055994531f

typedef float f32x16 __attribute__((ext_vector_type(16)));
typedef short bf16x8 __attribute__((ext_vector_type(8)));

static __device__ __forceinline__ short f2bf(float f) {
    unsigned u = __float_as_uint(f);
    u += 0x7FFFu + ((u >> 16) & 1u);       // RNE (setup only)
    return (short)(u >> 16);
}
static __device__ __forceinline__ float bf2f(short s) {
    return __uint_as_float(((unsigned)(unsigned short)s) << 16);
}
static __device__ __forceinline__ unsigned pk2(float lo, float hi) {
    unsigned r;
    asm("v_cvt_pk_bf16_f32 %0, %1, %2" : "=v"(r) : "v"(lo), "v"(hi));
    return r;
}

// Segmented CRF forward, 32 batches/block, 32x32x16 MFMA, fused combine.
// R17 = R16 with the crash fixed: mask-window staging is SCALAR loads
// (R16's int4 read was misaligned (i0 % 4 == 1) and ran 1 element past the
// end of `mask` on the last row). Fixed 2^-7 per-masked-step rescale folded
// into ea; exponent ledger K += 7 lane-local. P=64/OV=3 -> 11-step chains.
__launch_bounds__(TPB, 1)
__global__ void crf_seg32(const float* __restrict__ logits,
                          const int*   __restrict__ tags,
                          const int*   __restrict__ mask,
                          const float* __restrict__ trans,
                          const float* __restrict__ startt,
                          const float* __restrict__ endt,
                          float* __restrict__ out)
{
    const int sid = blockIdx.x & (P - 1);
    const int grp = blockIdx.x >> 6;
    const int b0 = grp * G;
    const int t = threadIdx.x;
    const int T = t >> 6;          // wave -> j-tile [32T, 32T+32)
    const int l = t & 63;
    const int n = l & 31;          // batch column
    const int h = l >> 5;          // half 0/1

    const int i0 = sid ? sid * SEGL - OV : 0;
    const int qs = sid * SEGL;
    const int i1 = (sid == P - 1) ? SEQ - 1 : (sid + 1) * SEGL;

    __shared__ short AT[2][G][STRIDE];
    __shared__ float nred[6][G];
    __shared__ int   cred[6][G];
    __shared__ float expend_s[NT];

    if (t < NT) expend_s[t] = __expf(endt[t]);

    // per-lane mask window bits: bit d = mask[b0+n][i0+d], d in [0, i1-i0] (<=11)
    unsigned mybits = 0;
    {
        const int* mrow = mask + (size_t)(b0 + n) * SEQ + i0;
        const int wlen = i1 - i0 + 1;
        for (int d = 0; d < wlen; ++d)
            if (mrow[d]) mybits |= 1u << d;
    }

    // A-fragments with the fixed rescale folded in:
    // ea[c][e] = bf16( exp(T[16c+8h+e][32T+n]) * 2^-7 )
    bf16x8 ea[6];
#pragma unroll
    for (int c = 0; c < 6; ++c)
#pragma unroll
        for (int e = 0; e < 8; ++e)
            ea[c][e] = f2bf(__expf(trans[(16 * c + 8 * h + e) * NT + 32 * T + n])
                            * 0.0078125f);

    const float* emg = logits + (size_t)(b0 + n) * SEQ * NT;
    const int jb = 32 * T + 4 * h;         // group p base: jb + 8p

    // init state at i0: lane owns rows jb+8p+{0..3}, p=0..3, of batch n
    uint2 prev[4];
#pragma unroll
    for (int p = 0; p < 4; ++p) {
        uint2 pv;
        if (sid == 0) {
            const int j = jb + 8 * p;
            pv.x = pk2(__expf(startt[j + 0] + emg[j + 0]),
                       __expf(startt[j + 1] + emg[j + 1]));
            pv.y = pk2(__expf(startt[j + 2] + emg[j + 2]),
                       __expf(startt[j + 3] + emg[j + 3]));
        } else {
            pv.x = 0x3F803F80u; pv.y = 0x3F803F80u;   // ones
        }
        prev[p] = pv;
        *(uint2*)&AT[0][n][jb + 8 * p] = pv;
    }

    int K = 0;   // exponent ledger: stored = true * 2^-K; K += 7 per masked step

    // emission prefetch (depth 2): 4 float4 groups at rows jb+8p
    float4 eA[4], eB[4];
#pragma unroll
    for (int p = 0; p < 4; ++p) {
        eA[p] = *(const float4*)&emg[(size_t)(i0 + 1) * NT + jb + 8 * p];
        eB[p] = *(const float4*)&emg[(size_t)(i0 + 2) * NT + jb + 8 * p];
    }
    __syncthreads();

#define CRF_STEP(i) do {                                                       \
    const int d_ = (i) - i0;                                                   \
    const int rb_ = (d_ - 1) & 1, wb_ = d_ & 1;                                \
    bf16x8 Bf[6];                                                              \
    _Pragma("unroll")                                                          \
    for (int c = 0; c < 6; ++c)                                                \
        Bf[c] = *(const bf16x8*)&AT[rb_][n][16 * c + 8 * h];                   \
    const int ip_ = ((i) + 2 <= i1) ? (i) + 2 : i1;                            \
    float4 en_[4];                                                             \
    _Pragma("unroll")                                                          \
    for (int p = 0; p < 4; ++p)                                                \
        en_[p] = *(const float4*)&emg[(size_t)ip_ * NT + jb + 8 * p];          \
    const unsigned mk = (mybits >> d_) & 1u;                                   \
    float wsv[4][4];                                                           \
    _Pragma("unroll")                                                          \
    for (int p = 0; p < 4; ++p) {                                              \
        wsv[p][0] = __expf(eA[p].x); wsv[p][1] = __expf(eA[p].y);              \
        wsv[p][2] = __expf(eA[p].z); wsv[p][3] = __expf(eA[p].w);              \
    }                                                                          \
    f32x16 acc = {0.f,0.f,0.f,0.f,0.f,0.f,0.f,0.f,                             \
                  0.f,0.f,0.f,0.f,0.f,0.f,0.f,0.f};                            \
    _Pragma("unroll")                                                          \
    for (int c = 0; c < 6; ++c)                                                \
        acc = __builtin_amdgcn_mfma_f32_32x32x16_bf16(ea[c], Bf[c], acc, 0, 0, 0); \
    _Pragma("unroll")                                                          \
    for (int p = 0; p < 4; ++p) {                                              \
        const float av0 = acc[4 * p + 0] * wsv[p][0];                          \
        const float av1 = acc[4 * p + 1] * wsv[p][1];                          \
        const float av2 = acc[4 * p + 2] * wsv[p][2];                          \
        const float av3 = acc[4 * p + 3] * wsv[p][3];                          \
        uint2 nw; nw.x = pk2(av0, av1); nw.y = pk2(av2, av3);                  \
        if (mk) prev[p] = nw;                                                  \
        *(uint2*)&AT[wb_][n][jb + 8 * p] = prev[p];                            \
    }                                                                          \
    if (mk) K += FSH;                                                          \
    _Pragma("unroll")                                                          \
    for (int p = 0; p < 4; ++p) { eA[p] = eB[p]; eB[p] = en_[p]; }             \
    asm volatile("s_waitcnt lgkmcnt(0)\n\ts_barrier" ::: "memory");            \
} while (0)

    // warm-up (sid>0): steps i0+1..qs, then Lin snapshot into a register
    for (int i = i0 + 1; i <= qs; ++i) CRF_STEP(i);
    float Lin = 0.f;
    if (sid > 0 && t < G) {
        const int pb = (qs - i0) & 1;      // = OV&1 = 1
        float sd = 0.f;
        for (int j = 0; j < NT; ++j) sd += bf2f(AT[pb][t][j]);
        Lin = __logf(sd) + (float)K * LN2;
    }
    // main segment: steps qs+1..i1
    for (int i = qs + 1; i <= i1; ++i) CRF_STEP(i);

    float Lend_or_Lout = 0.f;
    {
        const int pb = (i1 - i0) & 1;
        if (t < G) {
            float s1 = 0.f, s2 = 0.f;
            for (int j = 0; j < NT; ++j) {
                const float a = bf2f(AT[pb][t][j]);
                s1 += a; s2 += a * expend_s[j];
            }
            const float su = (sid == P - 1) ? s2 : s1;
            Lend_or_Lout = __logf(su) + (float)K * LN2;
        }
    }

    // ---- numerator partials for steps qs+1..i1: chunk c (0..5), batch gn ----
    const int c = t >> 5;
    const int gn = t & 31;
    const float* emp = logits + (size_t)(b0 + gn) * SEQ * NT;
    const int* tgp = tags + (size_t)(b0 + gn) * SEQ;
    float pn = 0.f;
    for (int i = qs + 1 + c; i <= i1; i += 6) {
        if (mask[(size_t)(b0 + gn) * SEQ + i]) {
            const int tp = tgp[i - 1], tc = tgp[i];
            pn += trans[tp * NT + tc] + emp[(size_t)i * NT + tc];
        }
    }
    int pc = 0;
    if (sid == P - 1) {
        const int4* m4p = (const int4*)(mask + (size_t)(b0 + gn) * SEQ);
        for (int k = c; k < SEQ / 4; k += 6) {
            const int4 m4 = m4p[k];
            pc += (m4.x != 0) + (m4.y != 0) + (m4.z != 0) + (m4.w != 0);
        }
    }
    nred[c][gn] = pn; cred[c][gn] = pc;
    __syncthreads();

    if (t < G) {
        float num = 0.f; int cnt = 0;
        for (int cc = 0; cc < 6; ++cc) { num += nred[cc][t]; cnt += cred[cc][t]; }
        const int* tgq = tags + (size_t)(b0 + t) * SEQ;
        if (sid == 0)
            num += startt[tgq[0]] + logits[(size_t)(b0 + t) * SEQ * NT + tgq[0]];
        if (sid == P - 1)
            num += endt[tgq[cnt - 1]];

        float v = num - Lend_or_Lout + Lin;
        v += __shfl_xor(v, 1);
        v += __shfl_xor(v, 2);
        v += __shfl_xor(v, 4);
        v += __shfl_xor(v, 8);
        v += __shfl_xor(v, 16);
        if (t == 0) atomicAdd(out, v);
    }
}

extern "C" void kernel_launch(void* const* d_in, const int* in_sizes, int n_in,
                              void* d_out, int out_size, void* d_ws, size_t ws_size,
                              hipStream_t stream)
{
    const float* logits = (const float*)d_in[0];
    const int*   tags   = (const int*)  d_in[1];
    const int*   mask   = (const int*)  d_in[2];
    const float* trans  = (const float*)d_in[3];
    const float* startt = (const float*)d_in[4];
    const float* endt   = (const float*)d_in[5];
    float* out = (float*)d_out;

    hipMemsetAsync(out, 0, out_size * sizeof(float), stream);
    crf_seg32<<<(NBAT / G) * P, TPB, 0, stream>>>(logits, tags, mask, trans,
                                                  startt, endt, out);
}

// Round 18
// 41.365 us; speedup vs baseline: 1.3659x; 1.2307x over previous
//
#include <hip/hip_runtime.h>

#define SEQ 512
#define NBAT 512
#define NT 96
#define G 64
#define P 32
#define SEGL (SEQ / P)        // 16 steps per segment
#define OV 3                  // warm-up overlap (contraction ~10x/step -> 1e-3)
#define TPB 384               // 6 waves: (T = j-tile 0..2) x (M = n-tile 0..1)
#define STRIDE 104            // shorts; 208B row = 13 x 16B
#define FSH 7                 // fixed per-step rescale 2^-7 (folded into ea)
#define LN2 0.69314718055994531f

typedef float f32x16 __attribute__((ext_vector_type(16)));
typedef short bf16x8 __attribute__((ext_vector_type(8)));

static __device__ __forceinline__ short f2bf(float f) {
    unsigned u = __float_as_uint(f);
    u += 0x7FFFu + ((u >> 16) & 1u);       // RNE (setup only)
    return (short)(u >> 16);
}
static __device__ __forceinline__ float bf2f(short s) {
    return __uint_as_float(((unsigned)(unsigned short)s) << 16);
}
static __device__ __forceinline__ unsigned pk2(float lo, float hi) {
    unsigned r;
    asm("v_cvt_pk_bf16_f32 %0, %1, %2" : "=v"(r) : "v"(lo), "v"(hi));
    return r;
}

// Segmented CRF forward: 64 batches/block, ONE block per CU (256 blocks),
// 6 waves = 3 j-tiles x 2 n-tiles of 32x32x16 MFMA. Per-wave ea table is a
// single j-tile (24 VGPR) -- register-cheap. Fixed 2^-7 per-masked-step
// rescale folded into ea (K += 7 lane-local). Telescoping combine fused.
__launch_bounds__(TPB, 1)
__global__ void crf_seg64(const float* __restrict__ logits,
                          const int*   __restrict__ tags,
                          const int*   __restrict__ mask,
                          const float* __restrict__ trans,
                          const float* __restrict__ startt,
                          const float* __restrict__ endt,
                          float* __restrict__ out)
{
    const int sid = blockIdx.x & (P - 1);
    const int grp = blockIdx.x >> 5;
    const int b0 = grp * G;
    const int t = threadIdx.x;
    const int W = t >> 6;          // wave 0..5
    const int T = W >> 1;          // j-tile 0..2
    const int M = W & 1;           // n-tile 0..1
    const int l = t & 63;
    const int n = l & 31;          // batch within n-tile
    const int h = l >> 5;          // half 0/1
    const int bm = 32 * M + n;     // batch within block (0..63)

    const int i0 = sid ? sid * SEGL - OV : 0;
    const int qs = sid * SEGL;
    const int i1 = (sid == P - 1) ? SEQ - 1 : (sid + 1) * SEGL;

    __shared__ short AT[2][G][STRIDE];
    __shared__ float nred[6][G];
    __shared__ int   cred[6][G];
    __shared__ float expend_s[NT];

    if (t < NT) expend_s[t] = __expf(endt[t]);

    // per-lane mask window bits for batch b0+bm (scalar loads; window <= 19)
    unsigned mybits = 0;
    {
        const int* mrow = mask + (size_t)(b0 + bm) * SEQ + i0;
        const int wlen = i1 - i0 + 1;
        for (int d = 0; d < wlen; ++d)
            if (mrow[d]) mybits |= 1u << d;
    }

    // A-fragments for MY j-tile only: ea[c][e] = bf16(exp(T[16c+8h+e][32T+n]) * 2^-7)
    bf16x8 ea[6];
#pragma unroll
    for (int c = 0; c < 6; ++c)
#pragma unroll
        for (int e = 0; e < 8; ++e)
            ea[c][e] = f2bf(__expf(trans[(16 * c + 8 * h + e) * NT + 32 * T + n])
                            * 0.0078125f);

    const float* emg = logits + (size_t)(b0 + bm) * SEQ * NT;
    const int jb = 32 * T + 4 * h;         // C-row group base: jb + 8p

    // init state at i0: lane owns rows jb+8p+{0..3} of batch bm
    uint2 prev[4];
#pragma unroll
    for (int p = 0; p < 4; ++p) {
        uint2 pv;
        if (sid == 0) {
            const int j = jb + 8 * p;
            pv.x = pk2(__expf(startt[j + 0] + emg[j + 0]),
                       __expf(startt[j + 1] + emg[j + 1]));
            pv.y = pk2(__expf(startt[j + 2] + emg[j + 2]),
                       __expf(startt[j + 3] + emg[j + 3]));
        } else {
            pv.x = 0x3F803F80u; pv.y = 0x3F803F80u;   // ones
        }
        prev[p] = pv;
        *(uint2*)&AT[0][bm][jb + 8 * p] = pv;
    }

    int K = 0;   // exponent ledger: stored = true * 2^-K; K += 7 per masked step

    // emission prefetch (depth 2)
    float4 eA[4], eB[4];
#pragma unroll
    for (int p = 0; p < 4; ++p) {
        eA[p] = *(const float4*)&emg[(size_t)(i0 + 1) * NT + jb + 8 * p];
        eB[p] = *(const float4*)&emg[(size_t)(i0 + 2) * NT + jb + 8 * p];
    }
    __syncthreads();

#define CRF_STEP(i) do {                                                       \
    const int d_ = (i) - i0;                                                   \
    const int rb_ = (d_ - 1) & 1, wb_ = d_ & 1;                                \
    bf16x8 Bf[6];                                                              \
    _Pragma("unroll")                                                          \
    for (int c = 0; c < 6; ++c)                                                \
        Bf[c] = *(const bf16x8*)&AT[rb_][bm][16 * c + 8 * h];                  \
    const int ip_ = ((i) + 2 <= i1) ? (i) + 2 : i1;                            \
    float4 en_[4];                                                             \
    _Pragma("unroll")                                                          \
    for (int p = 0; p < 4; ++p)                                                \
        en_[p] = *(const float4*)&emg[(size_t)ip_ * NT + jb + 8 * p];          \
    const unsigned mk = (mybits >> d_) & 1u;                                   \
    float wsv[4][4];                                                           \
    _Pragma("unroll")                                                          \
    for (int p = 0; p < 4; ++p) {                                              \
        wsv[p][0] = __expf(eA[p].x); wsv[p][1] = __expf(eA[p].y);              \
        wsv[p][2] = __expf(eA[p].z); wsv[p][3] = __expf(eA[p].w);              \
    }                                                                          \
    f32x16 acc = {0.f,0.f,0.f,0.f,0.f,0.f,0.f,0.f,                             \
                  0.f,0.f,0.f,0.f,0.f,0.f,0.f,0.f};                            \
    _Pragma("unroll")                                                          \
    for (int c = 0; c < 6; ++c)                                                \
        acc = __builtin_amdgcn_mfma_f32_32x32x16_bf16(ea[c], Bf[c], acc, 0, 0, 0); \
    _Pragma("unroll")                                                          \
    for (int p = 0; p < 4; ++p) {                                              \
        const float av0 = acc[4 * p + 0] * wsv[p][0];                          \
        const float av1 = acc[4 * p + 1] * wsv[p][1];                          \
        const float av2 = acc[4 * p + 2] * wsv[p][2];                          \
        const float av3 = acc[4 * p + 3] * wsv[p][3];                          \
        uint2 nw; nw.x = pk2(av0, av1); nw.y = pk2(av2, av3);                  \
        if (mk) prev[p] = nw;                                                  \
        *(uint2*)&AT[wb_][bm][jb + 8 * p] = prev[p];                           \
    }                                                                          \
    if (mk) K += FSH;                                                          \
    _Pragma("unroll")                                                          \
    for (int p = 0; p < 4; ++p) { eA[p] = eB[p]; eB[p] = en_[p]; }             \
    asm volatile("s_waitcnt lgkmcnt(0)\n\ts_barrier" ::: "memory");            \
} while (0)

    // warm-up (sid>0): steps i0+1..qs, then Lin snapshot into a register
    for (int i = i0 + 1; i <= qs; ++i) CRF_STEP(i);

    const bool fin = (T == 0) && (h == 0);   // finalizer thread for batch bm
    float Lin = 0.f;
    if (sid > 0 && fin) {
        const int pb = (qs - i0) & 1;        // = OV&1 = 1
        float sd = 0.f;
        for (int j = 0; j < NT; ++j) sd += bf2f(AT[pb][bm][j]);
        Lin = __logf(sd) + (float)K * LN2;
    }
    // main segment: steps qs+1..i1
    for (int i = qs + 1; i <= i1; ++i) CRF_STEP(i);

    float Lend_or_Lout = 0.f;
    if (fin) {
        const int pb = (i1 - i0) & 1;
        float s1 = 0.f, s2 = 0.f;
        for (int j = 0; j < NT; ++j) {
            const float a = bf2f(AT[pb][bm][j]);
            s1 += a; s2 += a * expend_s[j];
        }
        const float su = (sid == P - 1) ? s2 : s1;
        Lend_or_Lout = __logf(su) + (float)K * LN2;
    }

    // ---- numerator partials for steps qs+1..i1: chunk W (0..5), batch l (0..63) ----
    {
        const float* emp = logits + (size_t)(b0 + l) * SEQ * NT;
        const int* tgp = tags + (size_t)(b0 + l) * SEQ;
        float pn = 0.f;
        for (int i = qs + 1 + W; i <= i1; i += 6) {
            if (mask[(size_t)(b0 + l) * SEQ + i]) {
                const int tp = tgp[i - 1], tc = tgp[i];
                pn += trans[tp * NT + tc] + emp[(size_t)i * NT + tc];
            }
        }
        int pc = 0;
        if (sid == P - 1) {
            const int4* m4p = (const int4*)(mask + (size_t)(b0 + l) * SEQ);
            for (int k = W; k < SEQ / 4; k += 6) {
                const int4 m4 = m4p[k];
                pc += (m4.x != 0) + (m4.y != 0) + (m4.z != 0) + (m4.w != 0);
            }
        }
        nred[W][l] = pn; cred[W][l] = pc;
    }
    __syncthreads();

    if (fin) {
        float num = 0.f; int cnt = 0;
        for (int cc = 0; cc < 6; ++cc) { num += nred[cc][bm]; cnt += cred[cc][bm]; }
        const int* tgq = tags + (size_t)(b0 + bm) * SEQ;
        if (sid == 0)
            num += startt[tgq[0]] + logits[(size_t)(b0 + bm) * SEQ * NT + tgq[0]];
        if (sid == P - 1)
            num += endt[tgq[cnt - 1]];
        nred[0][bm] = num - Lend_or_Lout + Lin;   // own column: no hazard
    }
    __syncthreads();

    if (t == 0) {
        float s = 0.f;
        for (int b = 0; b < G; ++b) s += nred[0][b];
        atomicAdd(out, s);
    }
}

extern "C" void kernel_launch(void* const* d_in, const int* in_sizes, int n_in,
                              void* d_out, int out_size, void* d_ws, size_t ws_size,
                              hipStream_t stream)
{
    const float* logits = (const float*)d_in[0];
    const int*   tags   = (const int*)  d_in[1];
    const int*   mask   = (const int*)  d_in[2];
    const float* trans  = (const float*)d_in[3];
    const float* startt = (const float*)d_in[4];
    const float* endt   = (const float*)d_in[5];
    float* out = (float*)d_out;

    hipMemsetAsync(out, 0, out_size * sizeof(float), stream);
    crf_seg64<<<(NBAT / G) * P, TPB, 0, stream>>>(logits, tags, mask, trans,
                                                  startt, endt, out);
}

// Round 19
// 39.856 us; speedup vs baseline: 1.4176x; 1.0379x over previous
//
#include <hip/hip_runtime.h>

#define SEQ 512
#define NBAT 512
#define NT 96
#define G 64
#define P 32
#define SEGL (SEQ / P)        // 16 steps per segment
#define OV 3                  // warm-up overlap (contraction ~10x/step -> 1e-3)
#define TPB 384               // 6 waves: (T = j-tile 0..2) x (M = n-tile 0..1)
#define STRIDE 104            // shorts; 208B row = 13 x 16B
#define FSH 7                 // fixed per-step rescale 2^-7 (folded into ea)
#define LN2 0.69314718055994531f

typedef float f32x16 __attribute__((ext_vector_type(16)));
typedef short bf16x8 __attribute__((ext_vector_type(8)));

static __device__ __forceinline__ short f2bf(float f) {
    unsigned u = __float_as_uint(f);
    u += 0x7FFFu + ((u >> 16) & 1u);       // RNE (setup only)
    return (short)(u >> 16);
}
static __device__ __forceinline__ float bf2f(short s) {
    return __uint_as_float(((unsigned)(unsigned short)s) << 16);
}
static __device__ __forceinline__ unsigned pk2(float lo, float hi) {
    unsigned r;
    asm("v_cvt_pk_bf16_f32 %0, %1, %2" : "=v"(r) : "v"(lo), "v"(hi));
    return r;
}

// Segmented CRF forward: 64 batches/block, 1 block/CU, 6 waves (3 j-tiles x
// 2 n-tiles, 32x32x16 MFMA). R19: em is COALESCED-staged -- threads load the
// next step's 64x96 em tile with dense float4 runs, exp+cvt_pk to bf16, and
// ds_write_b64 into a TRANSPOSED swizzled LDS tile (pos = c*64 + (r^(c&7)));
// compute lanes read 4 b64 chunks back. This removes the per-lane-row
// scattered global loads (~768 L1 line-lookups per CU-step) that the R7-R18
// invariant ~1.1us/unit pointed to. Fixed 2^-7 rescale ledger (K += 7).
__launch_bounds__(TPB, 1)
__global__ void crf_seg64(const float* __restrict__ logits,
                          const int*   __restrict__ tags,
                          const int*   __restrict__ mask,
                          const float* __restrict__ trans,
                          const float* __restrict__ startt,
                          const float* __restrict__ endt,
                          float* __restrict__ out)
{
    const int sid = blockIdx.x & (P - 1);
    const int grp = blockIdx.x >> 5;
    const int b0 = grp * G;
    const int t = threadIdx.x;
    const int W = t >> 6;          // wave 0..5
    const int T = W >> 1;          // j-tile 0..2
    const int M = W & 1;           // n-tile 0..1
    const int l = t & 63;
    const int n = l & 31;          // batch within n-tile
    const int h = l >> 5;          // half 0/1
    const int bm = 32 * M + n;     // batch within block (0..63)

    const int i0 = sid ? sid * SEGL - OV : 0;
    const int qs = sid * SEGL;
    const int i1 = (sid == P - 1) ? SEQ - 1 : (sid + 1) * SEGL;
    const int dmax = i1 - i0;      // 16..19

    __shared__ short AT[2][G][STRIDE];       // bf16 state, double-buffered
    __shared__ uint2 EMS[2][1536];           // bf16 exp(em) tile, transposed+swizzled
    __shared__ float nred[6][G];
    __shared__ int   cred[6][G];
    __shared__ float expend_s[NT];

    if (t < NT) expend_s[t] = __expf(endt[t]);

    // ---- coalesced mask staging (bounce through EMS space, setup-only) ----
    const int wlen = dmax + 1;               // <= 20
    {
        int* mkS = (int*)&EMS[0][0];         // 64*20 ints = 5 KB, fits
        for (int f = t; f < G * wlen; f += TPB) {
            const int r = f / wlen, dd = f - r * wlen;
            mkS[f] = mask[(size_t)(b0 + r) * SEQ + i0 + dd];
        }
    }
    __syncthreads();
    unsigned mybits = 0;
    {
        const int* mkS = (const int*)&EMS[0][0];
        for (int dd = 0; dd < wlen; ++dd)
            if (mkS[bm * wlen + dd]) mybits |= 1u << dd;
    }
    __syncthreads();                         // EMS reused below

    // A-fragments: ea[c][e] = bf16(exp(T[16c+8h+e][32T+n]) * 2^-7)
    bf16x8 ea[6];
#pragma unroll
    for (int c = 0; c < 6; ++c)
#pragma unroll
        for (int e = 0; e < 8; ++e)
            ea[c][e] = f2bf(__expf(trans[(16 * c + 8 * h + e) * NT + 32 * T + n])
                            * 0.0078125f);

    const float* emg = logits + (size_t)(b0 + bm) * SEQ * NT;
    const int jb = 32 * T + 4 * h;           // C-row group base: jb + 8p

    // ---- staging slot tables ----
    // write side: thread t covers float4 chunks f = k*TPB + t -> (r = f/24, c = f%24)
    int wposv[4]; const float* gsrc[4];
#pragma unroll
    for (int k = 0; k < 4; ++k) {
        const int f = k * TPB + t;           // 0..1535
        const int r = f / 24, c = f - 24 * r;
        wposv[k] = c * 64 + (r ^ (c & 7));   // swizzled uint2 slot
        gsrc[k] = logits + (size_t)(b0 + r) * SEQ * NT + 4 * c;
    }
    // read side: lane needs chunks c = 8T + 2p + h of row bm
    int rposv[4];
#pragma unroll
    for (int p = 0; p < 4; ++p) {
        const int c = 8 * T + 2 * p + h;
        rposv[p] = c * 64 + (bm ^ (c & 7));
    }

    // init state at i0: lane owns rows jb+8p+{0..3} of batch bm
    uint2 prev[4];
#pragma unroll
    for (int p = 0; p < 4; ++p) {
        uint2 pv;
        if (sid == 0) {
            const int j = jb + 8 * p;
            pv.x = pk2(__expf(startt[j + 0] + emg[j + 0]),
                       __expf(startt[j + 1] + emg[j + 1]));
            pv.y = pk2(__expf(startt[j + 2] + emg[j + 2]),
                       __expf(startt[j + 3] + emg[j + 3]));
        } else {
            pv.x = 0x3F803F80u; pv.y = 0x3F803F80u;   // ones
        }
        prev[p] = pv;
        *(uint2*)&AT[0][bm][jb + 8 * p] = pv;
    }

    int K = 0;   // exponent ledger: stored = true * 2^-K; K += 7 per masked step

    // ---- prologue staging: EMS[1] <- em(i0+1); pA <- em(i0+2); pB <- em(i0+3)
    float4 pA[4], pB[4];
#pragma unroll
    for (int k = 0; k < 4; ++k) pA[k] = *(const float4*)(gsrc[k] + (size_t)(i0 + 1) * NT);
#pragma unroll
    for (int k = 0; k < 4; ++k)
        EMS[1][wposv[k]] = make_uint2(pk2(__expf(pA[k].x), __expf(pA[k].y)),
                                      pk2(__expf(pA[k].z), __expf(pA[k].w)));
#pragma unroll
    for (int k = 0; k < 4; ++k) pA[k] = *(const float4*)(gsrc[k] + (size_t)(i0 + 2) * NT);
#pragma unroll
    for (int k = 0; k < 4; ++k) pB[k] = *(const float4*)(gsrc[k] + (size_t)(i0 + 3) * NT);
    __syncthreads();

#define CRF_STEP(i, X) do {                                                    \
    const int d_ = (i) - i0;                                                   \
    const int rb_ = (d_ - 1) & 1, wb_ = d_ & 1;  /* cu_ = wb_, nx_ = rb_ */    \
    /* stage em(i+1): exp + pack X, swizzled transpose write */                \
    _Pragma("unroll")                                                          \
    for (int k = 0; k < 4; ++k)                                                \
        EMS[rb_ ^ 1 ^ wb_ ^ wb_][0] = EMS[rb_ ^ 1 ^ wb_ ^ wb_][0];            \
    _Pragma("unroll")                                                          \
    for (int k = 0; k < 4; ++k)                                                \
        EMS[wb_ ^ 1][wposv[k]] = make_uint2(pk2(__expf(X[k].x), __expf(X[k].y)), \
                                            pk2(__expf(X[k].z), __expf(X[k].w))); \
    /* reload X <- em(i+3), coalesced */                                       \
    { const int ip_ = ((i) + 3 <= i1) ? (i) + 3 : i1;                          \
      _Pragma("unroll")                                                        \
      for (int k = 0; k < 4; ++k)                                              \
          X[k] = *(const float4*)(gsrc[k] + (size_t)ip_ * NT); }               \
    bf16x8 Bf[6];                                                              \
    _Pragma("unroll")                                                          \
    for (int c = 0; c < 6; ++c)                                                \
        Bf[c] = *(const bf16x8*)&AT[rb_][bm][16 * c + 8 * h];                  \
    f32x16 acc = {0.f,0.f,0.f,0.f,0.f,0.f,0.f,0.f,                             \
                  0.f,0.f,0.f,0.f,0.f,0.f,0.f,0.f};                            \
    _Pragma("unroll")                                                          \
    for (int c = 0; c < 6; ++c)                                                \
        acc = __builtin_amdgcn_mfma_f32_32x32x16_bf16(ea[c], Bf[c], acc, 0, 0, 0); \
    const unsigned mk = (mybits >> d_) & 1u;                                   \
    _Pragma("unroll")                                                          \
    for (int p = 0; p < 4; ++p) {                                              \
        const uint2 wv = EMS[wb_][rposv[p]];                                   \
        const float w0 = __uint_as_float(wv.x << 16);                          \
        const float w1 = __uint_as_float(wv.x & 0xFFFF0000u);                  \
        const float w2 = __uint_as_float(wv.y << 16);                          \
        const float w3 = __uint_as_float(wv.y & 0xFFFF0000u);                  \
        uint2 nw;                                                              \
        nw.x = pk2(acc[4 * p + 0] * w0, acc[4 * p + 1] * w1);                  \
        nw.y = pk2(acc[4 * p + 2] * w2, acc[4 * p + 3] * w3);                  \
        if (mk) prev[p] = nw;                                                  \
        *(uint2*)&AT[wb_][bm][jb + 8 * p] = prev[p];                           \
    }                                                                          \
    if (mk) K += FSH;                                                          \
    asm volatile("s_waitcnt lgkmcnt(0)\n\ts_barrier" ::: "memory");            \
} while (0)

    const bool fin = (T == 0) && (h == 0);   // finalizer lanes (one per batch)
    float Lin = 0.f;

    for (int d = 1; d <= dmax; d += 2) {
        CRF_STEP(i0 + d, pA);
        if (sid && d == OV && fin) {         // Lin snapshot after step qs
            float sd = 0.f;
            for (int j = 0; j < NT; ++j) sd += bf2f(AT[OV & 1][bm][j]);
            Lin = __logf(sd) + (float)K * LN2;
        }
        if (d + 1 <= dmax) CRF_STEP(i0 + d + 1, pB);
    }

    float Lend_or_Lout = 0.f;
    if (fin) {
        const int pb = dmax & 1;
        float s1 = 0.f, s2 = 0.f;
        for (int j = 0; j < NT; ++j) {
            const float a = bf2f(AT[pb][bm][j]);
            s1 += a; s2 += a * expend_s[j];
        }
        const float su = (sid == P - 1) ? s2 : s1;
        Lend_or_Lout = __logf(su) + (float)K * LN2;
    }

    // ---- numerator partials for steps qs+1..i1: chunk W (0..5), batch l ----
    {
        const float* emp = logits + (size_t)(b0 + l) * SEQ * NT;
        const int* tgp = tags + (size_t)(b0 + l) * SEQ;
        float pn = 0.f;
        for (int i = qs + 1 + W; i <= i1; i += 6) {
            if (mask[(size_t)(b0 + l) * SEQ + i]) {
                const int tp = tgp[i - 1], tc = tgp[i];
                pn += trans[tp * NT + tc] + emp[(size_t)i * NT + tc];
            }
        }
        int pc = 0;
        if (sid == P - 1) {
            const int4* m4p = (const int4*)(mask + (size_t)(b0 + l) * SEQ);
            for (int k = W; k < SEQ / 4; k += 6) {
                const int4 m4 = m4p[k];
                pc += (m4.x != 0) + (m4.y != 0) + (m4.z != 0) + (m4.w != 0);
            }
        }
        nred[W][l] = pn; cred[W][l] = pc;
    }
    __syncthreads();

    if (fin) {
        float num = 0.f; int cnt = 0;
        for (int cc = 0; cc < 6; ++cc) { num += nred[cc][bm]; cnt += cred[cc][bm]; }
        const int* tgq = tags + (size_t)(b0 + bm) * SEQ;
        if (sid == 0)
            num += startt[tgq[0]] + logits[(size_t)(b0 + bm) * SEQ * NT + tgq[0]];
        if (sid == P - 1)
            num += endt[tgq[cnt - 1]];
        nred[0][bm] = num - Lend_or_Lout + Lin;
    }
    __syncthreads();

    if (t == 0) {
        float s = 0.f;
        for (int b = 0; b < G; ++b) s += nred[0][b];
        atomicAdd(out, s);
    }
}

extern "C" void kernel_launch(void* const* d_in, const int* in_sizes, int n_in,
                              void* d_out, int out_size, void* d_ws, size_t ws_size,
                              hipStream_t stream)
{
    const float* logits = (const float*)d_in[0];
    const int*   tags   = (const int*)  d_in[1];
    const int*   mask   = (const int*)  d_in[2];
    const float* trans  = (const float*)d_in[3];
    const float* startt = (const float*)d_in[4];
    const float* endt   = (const float*)d_in[5];
    float* out = (float*)d_out;

    hipMemsetAsync(out, 0, out_size * sizeof(float), stream);
    crf_seg64<<<(NBAT / G) * P, TPB, 0, stream>>>(logits, tags, mask, trans,
                                                  startt, endt, out);
}